// Round 16
// baseline (142.680 us; speedup 1.0000x reference)
//
#include <hip/hip_runtime.h>
#include <hip/hip_bf16.h>

// Problem dims (fixed by the reference)
constexpr int B_  = 4;
constexpr int S_  = 2048;
constexpr int D_  = 512;
constexpr int H_  = 8;
constexpr int HD_ = 64;
constexpr int M_  = B_ * S_;   // 8192

constexpr float LOG2E = 1.4426950408889634f;

typedef __attribute__((ext_vector_type(8))) short short8v;            // 8 bf16 (4 VGPR) MFMA operand
typedef __attribute__((ext_vector_type(8))) _Float16 half8v;          // 8 f16 (4 VGPR) MFMA operand
typedef __attribute__((ext_vector_type(8))) unsigned short ushort8v;  // 16B staging chunk
typedef __attribute__((ext_vector_type(4))) float float4v;            // 16x16 MFMA C/D
typedef __attribute__((ext_vector_type(16))) float float16v;          // 32x32 MFMA C/D

__device__ __forceinline__ unsigned short f2bf(float x) {  // RNE fp32->bf16
    unsigned u = __builtin_bit_cast(unsigned, x);
    u += 0x7fffu + ((u >> 16) & 1u);
    return (unsigned short)(u >> 16);
}
__device__ __forceinline__ float bf2f(unsigned short h) {
    return __builtin_bit_cast(float, ((unsigned)h) << 16);
}
__device__ __forceinline__ unsigned short f2h(float x) {   // RNE fp32->fp16 bits
    return __builtin_bit_cast(unsigned short, (_Float16)x);
}
__device__ __forceinline__ float fast_exp2(float x) {
#if __has_builtin(__builtin_amdgcn_exp2f)
    return __builtin_amdgcn_exp2f(x);
#else
    return exp2f(x);
#endif
}
// pack two f32 as [trunc-bf16(lo) | trunc-bf16(hi)<<16]  (1 v_perm)
__device__ __forceinline__ unsigned pack_bf16_trunc(float lo, float hi) {
    const unsigned ulo = __builtin_bit_cast(unsigned, lo);
    const unsigned uhi = __builtin_bit_cast(unsigned, hi);
#if __has_builtin(__builtin_amdgcn_perm)
    return __builtin_amdgcn_perm(uhi, ulo, 0x07060302u);
#else
    return (uhi & 0xffff0000u) | (ulo >> 16);
#endif
}
// async global->LDS, 16B per lane; lds dest = wave-uniform base + lane*16
__device__ __forceinline__ void gload_lds16(const void* g, void* lds) {
    __builtin_amdgcn_global_load_lds((const __attribute__((address_space(1))) unsigned*)g,
                                     (__attribute__((address_space(3))) unsigned*)lds, 16, 0, 0);
}

// ---------------------------------------------------------------------------
// Prepass: single-precision-tier operands.
//   Xf  [8192][512] f16(x);  Wf [1536][512] f16(w_qkv);  Wob bf16(w_out).
// ---------------------------------------------------------------------------
__global__ __launch_bounds__(256) void prepass(const float* __restrict__ x,
                                               const float* __restrict__ wqkv,
                                               const float* __restrict__ wout,
                                               unsigned short* __restrict__ Xf,
                                               unsigned short* __restrict__ Wf,
                                               unsigned short* __restrict__ Wob) {
    const int bid = blockIdx.x, t = threadIdx.x;
    if (bid < 2048) {                      // x -> f16
        const int flat = bid * 256 + t;
        const int m = flat >> 6, c = (flat & 63) * 8;
        const float4 a = *(const float4*)&x[(size_t)m * 512 + c];
        const float4 b = *(const float4*)&x[(size_t)m * 512 + c + 4];
        const float v[8] = {a.x, a.y, a.z, a.w, b.x, b.y, b.z, b.w};
        ushort8v o;
#pragma unroll
        for (int i = 0; i < 8; ++i) o[i] = f2h(v[i]);
        *(ushort8v*)&Xf[(size_t)m * 512 + c] = o;
    } else if (bid < 2048 + 384) {         // w_qkv -> f16
        const int flat = (bid - 2048) * 256 + t;
        const int e = flat >> 6, c = (flat & 63) * 8;
        const float4 a = *(const float4*)&wqkv[(size_t)e * 512 + c];
        const float4 b = *(const float4*)&wqkv[(size_t)e * 512 + c + 4];
        const float v[8] = {a.x, a.y, a.z, a.w, b.x, b.y, b.z, b.w};
        ushort8v o;
#pragma unroll
        for (int i = 0; i < 8; ++i) o[i] = f2h(v[i]);
        *(ushort8v*)&Wf[(size_t)e * 512 + c] = o;
    } else {                               // w_out -> bf16
        const int flat = (bid - 2432) * 256 + t;
        const int e = flat >> 6, c = (flat & 63) * 8;
        const float4 a = *(const float4*)&wout[(size_t)e * 512 + c];
        const float4 b = *(const float4*)&wout[(size_t)e * 512 + c + 4];
        const float v[8] = {a.x, a.y, a.z, a.w, b.x, b.y, b.z, b.w};
        ushort8v o;
#pragma unroll
        for (int i = 0; i < 8; ++i) o[i] = f2bf(v[i]);
        *(ushort8v*)&Wob[(size_t)e * 512 + c] = o;
    }
}

// ---------------------------------------------------------------------------
// GEMM1 (QKV projection): f16 single-pass, 128x128 tiles, BK=64, 8 iters,
// dbuf+prefetch, XCD swizzle. Slices: x>>2 = 0:q 1:k 2:v; e0=(x&3)*128.
// Grid (12,64). Q stored f16 pre-scaled by log2e; K f16; V bf16 j-permuted.
// ---------------------------------------------------------------------------
__global__ __launch_bounds__(256, 2) void gemm_qkv(const unsigned short* __restrict__ Xf,
                                                   const unsigned short* __restrict__ Wf,
                                                   unsigned short* __restrict__ Qf,
                                                   unsigned short* __restrict__ KH,
                                                   unsigned short* __restrict__ VT) {
    __shared__ unsigned short Asm[2][128 * 64];   // 32 KB (f16 bits)
    __shared__ unsigned short Bsm[2][128 * 64];   // 32 KB
    const int t = threadIdx.x, wv = t >> 6, lane = t & 63;
    const int fm = lane & 15, fq = lane >> 4;
    const int bid0 = blockIdx.x + 12 * blockIdx.y;
    const int xcd = bid0 & 7, ii = bid0 >> 3;       // ii in 0..95
    const int x  = ii % 12;
    const int m0 = ((ii / 12) * 8 + xcd) * 128;
    const int slice = x >> 2;            // 0=q 1=k 2=v
    const int e0 = (x & 3) * 128;        // within the 512-wide segment
    const bool vblk = (slice == 2);
    const int wrow = (wv >> 1) * 64, wcol = (wv & 1) * 64;

    const unsigned short* Bbase = Wf + (size_t)(e0 + slice * 512) * 512;

    const int srow = t >> 3;     // 0..31; +32*i extends
    const int skb0 = t & 7;

    float4v acc[4][4];
#pragma unroll
    for (int i = 0; i < 4; ++i)
#pragma unroll
        for (int j = 0; j < 4; ++j) acc[i][j] = (float4v){0.f, 0.f, 0.f, 0.f};

    // prologue: stage tile kk=0 into buf 0
#pragma unroll
    for (int i = 0; i < 4; ++i) {
        const int row = srow + 32 * i;
        const int kb = skb0 ^ (row & 7);
        gload_lds16(Xf + (size_t)(m0 + row) * 512 + kb * 8,
                    &Asm[0][(wv * 64 + 256 * i) * 8]);
        gload_lds16(Bbase + (size_t)row * 512 + kb * 8,
                    &Bsm[0][(wv * 64 + 256 * i) * 8]);
    }

    for (int kk = 0; kk < 8; ++kk) {
        __syncthreads();   // tile kk DMA complete; buf[(kk+1)&1] free

        if (kk + 1 < 8) {          // prefetch tile kk+1 (overlaps compute of kk)
            const int k0n = (kk + 1) * 64;
            const int nbuf = (kk + 1) & 1;
#pragma unroll
            for (int i = 0; i < 4; ++i) {
                const int row = srow + 32 * i;
                const int kb = skb0 ^ (row & 7);
                gload_lds16(Xf + (size_t)(m0 + row) * 512 + k0n + kb * 8,
                            &Asm[nbuf][(wv * 64 + 256 * i) * 8]);
                gload_lds16(Bbase + (size_t)row * 512 + k0n + kb * 8,
                            &Bsm[nbuf][(wv * 64 + 256 * i) * 8]);
            }
        }

        const int buf = kk & 1;
#pragma unroll
        for (int ks = 0; ks < 2; ++ks) {
            half8v af[4], bf[4];
#pragma unroll
            for (int mt = 0; mt < 4; ++mt) {
                const int row = wrow + mt * 16 + fm;
                af[mt] = *(const half8v*)&Asm[buf][row * 64 + 8 * ((4 * ks + fq) ^ (row & 7))];
            }
#pragma unroll
            for (int nt = 0; nt < 4; ++nt) {
                const int row = wcol + nt * 16 + fm;
                bf[nt] = *(const half8v*)&Bsm[buf][row * 64 + 8 * ((4 * ks + fq) ^ (row & 7))];
            }
            if (vblk) {
#pragma unroll
                for (int mt = 0; mt < 4; ++mt)
#pragma unroll
                    for (int nt = 0; nt < 4; ++nt)
                        acc[mt][nt] = __builtin_amdgcn_mfma_f32_16x16x32_f16(bf[nt], af[mt], acc[mt][nt], 0, 0, 0);
            } else {
#pragma unroll
                for (int mt = 0; mt < 4; ++mt)
#pragma unroll
                    for (int nt = 0; nt < 4; ++nt)
                        acc[mt][nt] = __builtin_amdgcn_mfma_f32_16x16x32_f16(af[mt], bf[nt], acc[mt][nt], 0, 0, 0);
            }
        }
    }

    if (!vblk) {
        // q: f16 store pre-scaled by log2e; k: f16 store
        unsigned short* __restrict__ dst = (slice == 0) ? Qf : KH;
        const float sc = (slice == 0) ? LOG2E : 1.0f;
#pragma unroll
        for (int mt = 0; mt < 4; ++mt)
#pragma unroll
            for (int nt = 0; nt < 4; ++nt) {
                const int e = e0 + wcol + nt * 16 + fm;
                const int h = e >> 6, hd = e & 63;
#pragma unroll
                for (int r = 0; r < 4; ++r) {
                    const int m = m0 + wrow + mt * 16 + 4 * fq + r;
                    const int b = m >> 11, s = m & 2047;
                    dst[((size_t)(b * 8 + h) * 2048 + s) * 64 + hd] =
                        f2h(acc[mt][nt][r] * sc);
                }
            }
    } else {
        // v: acc rows = e (4fq+r), cols = m (fm);
        // store at j-permuted column s2 (swap bits 2<->3 within 16-group)
#pragma unroll
        for (int nt = 0; nt < 4; ++nt)
#pragma unroll
            for (int r = 0; r < 4; ++r) {
                const int e = e0 + wcol + nt * 16 + 4 * fq + r;
                const int h = e >> 6, hd = e & 63;
#pragma unroll
                for (int mt = 0; mt < 4; ++mt) {
                    const int m = m0 + wrow + mt * 16 + fm;
                    const int b = m >> 11, s = m & 2047;
                    const int s2 = (s & ~12) | ((s & 4) << 1) | ((s & 8) >> 1);
                    VT[((size_t)(b * 8 + h) * 64 + hd) * 2048 + s2] = f2bf(acc[mt][nt][r]);
                }
            }
    }
}

// ---------------------------------------------------------------------------
// MFMA flash attention v16: KVBLK=128 -- amortize per-phase overhead.
// R15 post-mortem: attn flat at 46-48us across all geometries; accounting
// shows ~1800 cyc/phase of FIXED overhead (8-wave barrier + vmcnt(0) drain +
// MFMA chain fill) x 32 phases ~ 24us = half the kernel. v16 halves phase
// count: 128-j tiles, 16 phases, 1 barrier each; each phase has 4
// INDEPENDENT QK->exp2->PV chains (jb=0..3) for the scheduler + 2 waves/SIMD
// to interleave (4x chain-fill amortization, was 2x). Serial per-jb body
// keeps live regs ~110 (sS transient) -- no spill at the required 2 w/SIMD.
// Work conserved exactly (MFMA/exp2/LDS-reads/DMA per q-row unchanged).
// LDS: Ks dbuf 32KB + Vs dbuf 32KB = 64KB; 1 block/CU; grid 256 exact fill.
// Decision rule: attn >= 46us => overhead scales with work, plateau declared.
// ---------------------------------------------------------------------------
__global__ __launch_bounds__(512, 1) void attn(const unsigned short* __restrict__ Qfp,
                                               const unsigned short* __restrict__ KHp,
                                               const unsigned short* __restrict__ VTp,
                                               unsigned short* __restrict__ OB) {
    __shared__ unsigned short Ks[2][128 * 64];   // 32 KB, f16 K tiles [j][d], XOR-swizzled
    __shared__ unsigned short Vs[2][64 * 128];   // 32 KB, bf16 V^T tiles [d][j-perm], XOR-swizzled
    const int t = threadIdx.x, wv = t >> 6, lane = t & 63;
    const int lq = lane & 31;     // q (and d/j) index within 32
    const int hf2 = lane >> 5;    // half-wave
    // XCD swizzle: 256 blocks, xcd = bid%8; each XCD owns 4 bh (K/V L2-hot)
    const int bid0 = blockIdx.x + 8 * blockIdx.y;
    const int xcd = bid0 & 7, ii = bid0 >> 3;    // ii in 0..31
    const int bh = (ii & 3) * 8 + xcd;
    const int q0 = (ii >> 2) * 256;              // 8 q-tiles of 256

    const unsigned short* qfp = Qfp + (size_t)bh * S_ * 64;
    const unsigned short* kh  = KHp + (size_t)bh * S_ * 64;
    const unsigned short* vt  = VTp + (size_t)bh * 64 * S_;

// stage K tile N (128 rows x 64 d f16 = 16 KB) into Ks[B]; 512 thr x 2 passes.
// pass i: lane covers row = i*64 + wv*8 + (lane>>3), slot lane&7; global
// chunk = slot ^ (row&7) (row&7 == (lane>>3)&7 here). Dest linear per wave.
#define STAGE_K(N, B) do {                                                      \
    _Pragma("unroll")                                                           \
    for (int i_ = 0; i_ < 2; ++i_) {                                            \
        const int row_ = i_ * 64 + wv * 8 + (lane >> 3);                        \
        const int kb_ = (lane & 7) ^ ((lane >> 3) & 7);                         \
        gload_lds16(kh + (size_t)((N) * 128 + row_) * 64 + kb_ * 8,             \
                    &Ks[B][(i_ * 512 + wv * 64) * 8]);                          \
    } } while (0)

// stage V^T tile N (64 d-rows x 128 j = 16 KB) into Vs[B]; 2 passes.
// pass i: row = i*32 + wv*4 + (lane>>4), slot lane&15; global chunk =
// slot ^ (row&7). Dest linear per wave.
#define STAGE_V(N, B) do {                                                      \
    _Pragma("unroll")                                                           \
    for (int i_ = 0; i_ < 2; ++i_) {                                            \
        const int row_ = i_ * 32 + wv * 4 + (lane >> 4);                        \
        const int gc_ = (lane & 15) ^ (row_ & 7);                               \
        gload_lds16(vt + (size_t)row_ * S_ + (N) * 128 + gc_ * 8,               \
                    &Vs[B][(i_ * 512 + wv * 64) * 8]);                          \
    } } while (0)

    // prologue: stage K(0)->Ks[0], V(0)->Vs[0]
    STAGE_K(0, 0);
    STAGE_V(0, 0);

    // Q B-frags: direct f16 load (pre-scaled by log2e in gemm_qkv);
    // lane holds Q[q = q0+wv*32+lq][d = kk*16 + hf2*8 + i]
    half8v qf[4];
    {
        const int qrow = q0 + wv * 32 + lq;
#pragma unroll
        for (int kk = 0; kk < 4; ++kk)
            qf[kk] = *(const half8v*)&qfp[(size_t)qrow * 64 + kk * 16 + hf2 * 8];
    }

    float16v accO[2];
#pragma unroll
    for (int db = 0; db < 2; ++db)
#pragma unroll
        for (int r = 0; r < 16; ++r) accO[db][r] = 0.f;
    float lsum = 0.f;

    __syncthreads();            // prologue DMA complete

    // 16 phases; dbuf prefetch of tile n+1 overlaps compute of n; one
    // barrier per phase. Per phase: 4 independent jb chains.
    for (int n = 0; n < 16; ++n) {
        const int buf = n & 1;
        if (n + 1 < 16) {
            STAGE_K(n + 1, buf ^ 1);
            STAGE_V(n + 1, buf ^ 1);
        }

#pragma unroll
        for (int jb = 0; jb < 4; ++jb) {
            // S^T = K Q^T for j-block jb: lane reg 4g+r holds
            // S[q=lq][j = n*128 + jb*32 + r + 8g + 4*hf2]
            float16v sS;
#pragma unroll
            for (int r = 0; r < 16; ++r) sS[r] = 0.f;
            __builtin_amdgcn_s_setprio(1);
#pragma unroll
            for (int kk = 0; kk < 4; ++kk) {
                const int row = jb * 32 + lq;
                const int cb = 2 * kk + hf2;
                const half8v kf = *(const half8v*)&Ks[buf][row * 64 + 8 * (cb ^ (row & 7))];
                sS = __builtin_amdgcn_mfma_f32_32x32x16_f16(kf, qf[kk], sS, 0, 0, 0);
            }
            __builtin_amdgcn_s_setprio(0);

            // P = exp2(S); pack to permuted-k A-frag dwords; accumulate lsum
            unsigned pk[4][2];
#pragma unroll
            for (int g = 0; g < 4; ++g) {
                const float p0 = fast_exp2(sS[4 * g + 0]);
                const float p1 = fast_exp2(sS[4 * g + 1]);
                const float p2 = fast_exp2(sS[4 * g + 2]);
                const float p3 = fast_exp2(sS[4 * g + 3]);
                lsum += (p0 + p1) + (p2 + p3);
                pk[g][0] = pack_bf16_trunc(p0, p1);
                pk[g][1] = pack_bf16_trunc(p2, p3);
            }

            // O += P V for this j-block (chunks jc = jb*2 + {0,1})
            __builtin_amdgcn_s_setprio(1);
#pragma unroll
            for (int w = 0; w < 2; ++w) {
                const int jc = jb * 2 + w, gg = w * 2;
                const uint4 uu = {pk[gg][0], pk[gg][1], pk[gg + 1][0], pk[gg + 1][1]};
                const short8v pa = __builtin_bit_cast(short8v, uu);
#pragma unroll
                for (int db = 0; db < 2; ++db) {
                    const int vrow = db * 32 + lq;
                    const int cb2 = 2 * jc + hf2;
                    const short8v vf = *(const short8v*)&Vs[buf][vrow * 128 + 8 * (cb2 ^ (vrow & 7))];
                    accO[db] = __builtin_amdgcn_mfma_f32_32x32x16_bf16(pa, vf, accO[db], 0, 0, 0);
                }
            }
            __builtin_amdgcn_s_setprio(0);
        }

        __syncthreads();   // reads of buf done; DMA for buf^1 complete
    }

#undef STAGE_K
#undef STAGE_V

    // lane holds l-partial for q=lq over its half of j; combine halves
    const float ls = lsum + __shfl_xor(lsum, 32);
    const float invl = 1.f / ls;

    // epilogue: accO[db][4g+r] = O[q_local=r+8g+4*hf2][d=db*32+lq]
    const int b = bh >> 3, hh = bh & 7;
#pragma unroll
    for (int g = 0; g < 4; ++g)
#pragma unroll
        for (int r = 0; r < 4; ++r) {
            const int qrow = r + 8 * g + 4 * hf2;
            const float inv = __shfl(invl, qrow);   // lane qrow holds q=qrow
            const int q = q0 + wv * 32 + qrow;
#pragma unroll
            for (int db = 0; db < 2; ++db)
                OB[((size_t)(b * 2048 + q)) * 512 + hh * 64 + db * 32 + lq] =
                    f2bf(accO[db][4 * g + r] * inv);
        }
}

// ---------------------------------------------------------------------------
// GEMM2 (out projection): 128x128 tile, BK=64, dbuf + prefetch, bijective
// XCD swizzle. Grid (4,64) = 256 blocks.
// ---------------------------------------------------------------------------
__global__ __launch_bounds__(256, 2) void gemm_out(const unsigned short* __restrict__ OB,
                                                   const unsigned short* __restrict__ Wob,
                                                   float* __restrict__ out) {
    __shared__ unsigned short Asm[2][128 * 64];   // 32 KB
    __shared__ unsigned short Bsm[2][128 * 64];   // 32 KB
    const int t = threadIdx.x, wv = t >> 6, lane = t & 63;
    const int fm = lane & 15, fq = lane >> 4;
    const int bid0 = blockIdx.x + 4 * blockIdx.y;
    const int xcd = bid0 & 7, ii = bid0 >> 3;    // ii in 0..31
    const int e0 = (ii % 4) * 128;
    const int m0 = ((ii / 4) * 8 + xcd) * 128;
    const int wrow = (wv >> 1) * 64, wcol = (wv & 1) * 64;

    const int srow = t >> 3;
    const int skb0 = t & 7;

    float4v acc[4][4];
#pragma unroll
    for (int i = 0; i < 4; ++i)
#pragma unroll
        for (int j = 0; j < 4; ++j) acc[i][j] = (float4v){0.f, 0.f, 0.f, 0.f};

    // prologue: stage k0=0
#pragma unroll
    for (int i = 0; i < 4; ++i) {
        const int row = srow + 32 * i;
        const int kb = skb0 ^ (row & 7);
        gload_lds16(OB + (size_t)(m0 + row) * 512 + kb * 8,
                    &Asm[0][(wv * 64 + 256 * i) * 8]);
        gload_lds16(Wob + (size_t)(e0 + row) * 512 + kb * 8,
                    &Bsm[0][(wv * 64 + 256 * i) * 8]);
    }

    for (int kk = 0; kk < 8; ++kk) {
        __syncthreads();
        if (kk + 1 < 8) {
            const int k0n = (kk + 1) * 64, nbuf = (kk + 1) & 1;
#pragma unroll
            for (int i = 0; i < 4; ++i) {
                const int row = srow + 32 * i;
                const int kb = skb0 ^ (row & 7);
                gload_lds16(OB + (size_t)(m0 + row) * 512 + k0n + kb * 8,
                            &Asm[nbuf][(wv * 64 + 256 * i) * 8]);
                gload_lds16(Wob + (size_t)(e0 + row) * 512 + k0n + kb * 8,
                            &Bsm[nbuf][(wv * 64 + 256 * i) * 8]);
            }
        }
        const int buf = kk & 1;
#pragma unroll
        for (int ks = 0; ks < 2; ++ks) {
            short8v af[4], bf[4];
#pragma unroll
            for (int mt = 0; mt < 4; ++mt) {
                const int row = wrow + mt * 16 + fm;
                af[mt] = *(const short8v*)&Asm[buf][row * 64 + 8 * ((4 * ks + fq) ^ (row & 7))];
            }
#pragma unroll
            for (int nt = 0; nt < 4; ++nt) {
                const int row = wcol + nt * 16 + fm;
                bf[nt] = *(const short8v*)&Bsm[buf][row * 64 + 8 * ((4 * ks + fq) ^ (row & 7))];
            }
#pragma unroll
            for (int mt = 0; mt < 4; ++mt)
#pragma unroll
                for (int nt = 0; nt < 4; ++nt)
                    acc[mt][nt] = __builtin_amdgcn_mfma_f32_16x16x32_bf16(af[mt], bf[nt], acc[mt][nt], 0, 0, 0);
        }
    }
#pragma unroll
    for (int mt = 0; mt < 4; ++mt)
#pragma unroll
        for (int nt = 0; nt < 4; ++nt)
#pragma unroll
            for (int r = 0; r < 4; ++r) {
                const int m = m0 + wrow + mt * 16 + 4 * fq + r;
                const int e = e0 + wcol + nt * 16 + fm;
                out[(size_t)m * 512 + e] = acc[mt][nt][r];
            }
}

// ---------------------------------------------------------------------------
extern "C" void kernel_launch(void* const* d_in, const int* in_sizes, int n_in,
                              void* d_out, int out_size, void* d_ws, size_t ws_size,
                              hipStream_t stream) {
    const float* x     = (const float*)d_in[0];   // [B,S,D]
    const float* w_qkv = (const float*)d_in[1];   // [3D, D]
    const float* w_out = (const float*)d_in[2];   // [D, D]
    float* out = (float*)d_out;                   // [B,S,D]

    // workspace carve-up (bytes): total ~36 MB
    char* p = (char*)d_ws;
    unsigned short* Xf  = (unsigned short*)p;  p += (size_t)M_ * 512 * 2;       // 8.4 MB (f16)
    unsigned short* Wf  = (unsigned short*)p;  p += (size_t)1536 * 512 * 2;     // 1.6 MB (f16)
    unsigned short* Wob = (unsigned short*)p;  p += (size_t)512 * 512 * 2;      // 0.5 MB (bf16)
    unsigned short* Qf  = (unsigned short*)p;  p += (size_t)32 * S_ * 64 * 2;   // 8.4 MB (f16, x log2e)
    unsigned short* KH  = (unsigned short*)p;  p += (size_t)32 * S_ * 64 * 2;   // 8.4 MB (f16)
    unsigned short* VT  = (unsigned short*)p;  p += (size_t)32 * 64 * S_ * 2;   // 8.4 MB (bf16, j-permuted)
    unsigned short* OB  = Xf;  // Xf dead after gemm_qkv; reuse for attention output

    prepass<<<2560, 256, 0, stream>>>(x, w_qkv, w_out, Xf, Wf, Wob);
    gemm_qkv<<<dim3(12, 64), 256, 0, stream>>>(Xf, Wf, Qf, KH, VT);
    attn<<<dim3(8, 32), 512, 0, stream>>>(Qf, KH, VT, OB);
    gemm_out<<<dim3(4, 64), 256, 0, stream>>>(OB, Wob, out);
}